// Round 4
// baseline (320.475 us; speedup 1.0000x reference)
//
#include <hip/hip_runtime.h>

typedef float f32x4 __attribute__((ext_vector_type(4)));
typedef unsigned short u16x8 __attribute__((ext_vector_type(8)));
typedef __bf16 bf16x8 __attribute__((ext_vector_type(8)));

// ---------------------------------------------------------------------------
// Kernel 1: convert + transpose three W (fp32 [256 k][512 n]) into bf16 W^T
// [role][512 n][256 k] in workspace, via 64x64 LDS tile transpose.
// ---------------------------------------------------------------------------
__global__ __launch_bounds__(256) void convert_w_kernel(
    const float* __restrict__ Wt_, const float* __restrict__ Wi_,
    const float* __restrict__ Wo_, unsigned short* __restrict__ out)
{
    __shared__ unsigned short tile[64][72];

    const int b    = blockIdx.x;
    const int role = b >> 5;
    const int kt   = (b & 31) >> 3;
    const int nt   = b & 7;
    const float* __restrict__ W = (role == 0) ? Wt_ : ((role == 1) ? Wi_ : Wo_);

    const int t  = threadIdx.x;
    const int r0 = t >> 4;
    const int c4 = (t & 15) << 2;

#pragma unroll
    for (int j = 0; j < 4; ++j) {
        const int kl = r0 + j * 16;
        f32x4 v = *(const f32x4*)(W + (size_t)(kt * 64 + kl) * 512 + nt * 64 + c4);
#pragma unroll
        for (int e = 0; e < 4; ++e)
            tile[c4 + e][kl] = __builtin_bit_cast(unsigned short, (__bf16)v[e]);
    }
    __syncthreads();

    const int cs = t & 7;
#pragma unroll
    for (int p = 0; p < 2; ++p) {
        const int r = (t >> 3) + p * 32;
        u16x8 v = *(const u16x8*)&tile[r][cs * 8];
        *(u16x8*)(out + (size_t)role * 512 * 256 +
                  (size_t)(nt * 64 + r) * 256 + kt * 64 + cs * 8) = v;
    }
}

// ---------------------------------------------------------------------------
// Kernel 2: barrier-free streaming GEMM. No LDS, no __syncthreads.
// Grid = 4096 blocks x 256 threads (4 waves). Block = 256 exclusive rows x
// one 64-col strip; each wave owns 64 rows x 64 cols. A fragments are read
// directly from global fp32 (8 consecutive k per lane = 32 B contiguous),
// converted to bf16 in registers; W strip (32 KB bf16) is L1/L2-resident and
// shared by the block's 4 waves. Waves free-run -> loads/stores overlap via
// TLP with zero barrier drains.
// ---------------------------------------------------------------------------
__global__ __launch_bounds__(256, 3) void role_proj_kernel(
    const float* __restrict__ A,            // [131072][256] fp32
    const int* __restrict__ tmask,          // [64]
    const int* __restrict__ imask,          // [64]
    const unsigned short* __restrict__ Wws, // [3][512][256] bf16 (W^T)
    const float* __restrict__ bt, const float* __restrict__ bi,
    const float* __restrict__ bo,
    float* __restrict__ C)                  // [131072][512] fp32
{
    const int tid   = threadIdx.x;
    const int rg    = blockIdx.x >> 3;          // row group (256 rows)
    const int strip = blockIdx.x & 7;           // 64-col strip

    // role uniform per block: rows [rg*256, rg*256+255] -> t in [rg*4, rg*4+3]
    const int mi   = rg >> 3;
    const int role = tmask[mi] ? 0 : (imask[mi] ? 1 : 2);
    const unsigned short* __restrict__ W = Wws + (size_t)role * (512 * 256);
    const float* __restrict__ bias = (role == 0) ? bt : ((role == 1) ? bi : bo);

    const int lane  = tid & 63;
    const int wid   = tid >> 6;                 // 0..3: which 64-row slice
    const int l15   = lane & 15;
    const int l4    = lane >> 4;                // 0..3
    const int nbase = strip * 64;
    const int row0  = rg * 256 + wid * 64;

    // per-fm A fragment base (fp32): row = row0 + fm*16 + l15, k = l4*8
    const f32x4* ap[4];
#pragma unroll
    for (int fm = 0; fm < 4; ++fm)
        ap[fm] = (const f32x4*)(A + (size_t)(row0 + fm * 16 + l15) * 256 + l4 * 8);

    // per-fn W fragment base (bf16): n = nbase + fn*16 + l15, k = l4*8
    const unsigned short* wp[4];
#pragma unroll
    for (int fn = 0; fn < 4; ++fn)
        wp[fn] = W + (size_t)(nbase + fn * 16 + l15) * 256 + l4 * 8;

    f32x4 acc[4][4] = {};          // [fm][fn], 64 VGPRs

    // 1-deep A prefetch (HBM); B loads in-loop (L1-resident strip)
    f32x4 acur[4][2], anxt[4][2];
#pragma unroll
    for (int fm = 0; fm < 4; ++fm) {
        acur[fm][0] = __builtin_nontemporal_load(ap[fm]);
        acur[fm][1] = __builtin_nontemporal_load(ap[fm] + 1);
    }

#pragma unroll 1
    for (int ks = 0; ks < 8; ++ks) {
        if (ks < 7) {
#pragma unroll
            for (int fm = 0; fm < 4; ++fm) {
                const f32x4* p = ap[fm] + (ks + 1) * 8;   // +32 floats per ks
                anxt[fm][0] = __builtin_nontemporal_load(p);
                anxt[fm][1] = __builtin_nontemporal_load(p + 1);
            }
        }

        u16x8 bfr[4];
#pragma unroll
        for (int fn = 0; fn < 4; ++fn)
            bfr[fn] = *(const u16x8*)(wp[fn] + ks * 32);

        // convert A fragments fp32 -> bf16 in registers (v_cvt_pk_bf16_f32)
        bf16x8 abf[4];
#pragma unroll
        for (int fm = 0; fm < 4; ++fm) {
            abf[fm][0] = (__bf16)acur[fm][0][0]; abf[fm][1] = (__bf16)acur[fm][0][1];
            abf[fm][2] = (__bf16)acur[fm][0][2]; abf[fm][3] = (__bf16)acur[fm][0][3];
            abf[fm][4] = (__bf16)acur[fm][1][0]; abf[fm][5] = (__bf16)acur[fm][1][1];
            abf[fm][6] = (__bf16)acur[fm][1][2]; abf[fm][7] = (__bf16)acur[fm][1][3];
        }

#pragma unroll
        for (int fm = 0; fm < 4; ++fm) {
#pragma unroll
            for (int fn = 0; fn < 4; ++fn) {
                // swapped operands: acc row = out-channel (4 consecutive per
                // lane via reg idx), col = activation row -> float4 C stores
                acc[fm][fn] = __builtin_amdgcn_mfma_f32_16x16x32_bf16(
                    __builtin_bit_cast(bf16x8, bfr[fn]),
                    abf[fm],
                    acc[fm][fn], 0, 0, 0);
            }
        }

#pragma unroll
        for (int fm = 0; fm < 4; ++fm) {
            acur[fm][0] = anxt[fm][0];
            acur[fm][1] = anxt[fm][1];
        }
    }

    // --- epilogue: bias + nontemporal float4 stores
#pragma unroll
    for (int fn = 0; fn < 4; ++fn) {
        const int col = nbase + fn * 16 + l4 * 4;
        const f32x4 bv = *(const f32x4*)(bias + col);
#pragma unroll
        for (int fm = 0; fm < 4; ++fm) {
            const int row = row0 + fm * 16 + l15;
            f32x4 v = acc[fm][fn] + bv;
            __builtin_nontemporal_store(v, (f32x4*)(C + (size_t)row * 512 + col));
        }
    }
}

extern "C" void kernel_launch(void* const* d_in, const int* in_sizes, int n_in,
                              void* d_out, int out_size, void* d_ws, size_t ws_size,
                              hipStream_t stream) {
    const float* A   = (const float*)d_in[0];
    const int*   tm  = (const int*)d_in[1];
    const int*   im  = (const int*)d_in[2];
    const float* Wt_ = (const float*)d_in[3];
    const float* bt  = (const float*)d_in[4];
    const float* Wi_ = (const float*)d_in[5];
    const float* bi  = (const float*)d_in[6];
    const float* Wo_ = (const float*)d_in[7];
    const float* bo  = (const float*)d_in[8];

    unsigned short* Wws = (unsigned short*)d_ws;   // 3*512*256*2 = 768 KB

    hipLaunchKernelGGL(convert_w_kernel, dim3(96), dim3(256),
                       0, stream, Wt_, Wi_, Wo_, Wws);

    hipLaunchKernelGGL(role_proj_kernel, dim3(4096), dim3(256),
                       0, stream, A, tm, im, Wws, bt, bi, bo, (float*)d_out);
}

// Round 5
// 137.392 us; speedup vs baseline: 2.3326x; 2.3326x over previous
//
#include <hip/hip_runtime.h>

typedef float f32x4 __attribute__((ext_vector_type(4)));
typedef unsigned short u16x8 __attribute__((ext_vector_type(8)));
typedef __bf16 bf16x8 __attribute__((ext_vector_type(8)));

// ---------------------------------------------------------------------------
// Kernel 1: convert + transpose three W (fp32 [256 k][512 n]) into bf16 W^T
// [role][512 n][256 k] in workspace, via 64x64 LDS tile transpose.
// ---------------------------------------------------------------------------
__global__ __launch_bounds__(256) void convert_w_kernel(
    const float* __restrict__ Wt_, const float* __restrict__ Wi_,
    const float* __restrict__ Wo_, unsigned short* __restrict__ out)
{
    __shared__ unsigned short tile[64][72];

    const int b    = blockIdx.x;
    const int role = b >> 5;
    const int kt   = (b & 31) >> 3;
    const int nt   = b & 7;
    const float* __restrict__ W = (role == 0) ? Wt_ : ((role == 1) ? Wi_ : Wo_);

    const int t  = threadIdx.x;
    const int r0 = t >> 4;
    const int c4 = (t & 15) << 2;

#pragma unroll
    for (int j = 0; j < 4; ++j) {
        const int kl = r0 + j * 16;
        f32x4 v = *(const f32x4*)(W + (size_t)(kt * 64 + kl) * 512 + nt * 64 + c4);
#pragma unroll
        for (int e = 0; e < 4; ++e)
            tile[c4 + e][kl] = __builtin_bit_cast(unsigned short, (__bf16)v[e]);
    }
    __syncthreads();

    const int cs = t & 7;
#pragma unroll
    for (int p = 0; p < 2; ++p) {
        const int r = (t >> 3) + p * 32;
        u16x8 v = *(const u16x8*)&tile[r][cs * 8];
        *(u16x8*)(out + (size_t)role * 512 * 256 +
                  (size_t)(nt * 64 + r) * 256 + kt * 64 + cs * 8) = v;
    }
}

// ---------------------------------------------------------------------------
// Kernel 2: role-selected GEMM, fn-major streaming schedule.
// Grid = 2048 one-shot blocks (BM=64 rows, BN=512 = full width -> A read
// exactly once). 512 threads = 8 waves; wave owns 64x64. Single 32 KB LDS
// A-tile (fp32 -> bf16, XOR-swizzled), ONE barrier per block, no trailing
// barrier. fn-major inner schedule: acc = 16 VGPRs, each 64x16 col-strip's
// stores issue while the next strip computes (stores spread through the
// compute phase). NT only on read-once A loads; C stores CACHED so L2
// merges the 64 B chunks into full 128 B lines (round-4 fix: NT stores
// inflated WRITE_SIZE 1.37x). ~60 VGPR -> 3 blocks/CU staggered phases.
// ---------------------------------------------------------------------------
__global__ __launch_bounds__(512, 3) void role_proj_kernel(
    const float* __restrict__ A,            // [131072][256] fp32
    const int* __restrict__ tmask,          // [64]
    const int* __restrict__ imask,          // [64]
    const unsigned short* __restrict__ Wws, // [3][512][256] bf16 (W^T)
    const float* __restrict__ bt, const float* __restrict__ bi,
    const float* __restrict__ bo,
    float* __restrict__ C)                  // [131072][512] fp32
{
    __shared__ unsigned short As[64 * 256];  // 32 KB swizzled bf16 A tile

    const int tid = threadIdx.x;
    const int m0  = blockIdx.x * 64;

    // role uniform per block: mask index = t/32 = blockIdx/32
    const int mi   = blockIdx.x >> 5;
    const int role = tmask[mi] ? 0 : (imask[mi] ? 1 : 2);
    const unsigned short* __restrict__ W = Wws + (size_t)role * (512 * 256);
    const float* __restrict__ bias = (role == 0) ? bt : ((role == 1) ? bi : bo);

    // --- stage A tile: 64 rows x 256 k, fp32 -> bf16, swizzled LDS.
    // 8 x 16 B NT loads per thread issued back-to-back = 64 KB/block in
    // flight (deep read queue).
    f32x4 ld[4][2];
#pragma unroll
    for (int j = 0; j < 4; ++j) {
        const int u   = tid + 512 * j;
        const int row = u >> 5;
        const int sl  = u & 31;
        const f32x4* src = (const f32x4*)(A + (size_t)(m0 + row) * 256 + sl * 8);
        ld[j][0] = __builtin_nontemporal_load(src);
        ld[j][1] = __builtin_nontemporal_load(src + 1);
    }
#pragma unroll
    for (int j = 0; j < 4; ++j) {
        const int u   = tid + 512 * j;
        const int row = u >> 5;
        const int sl  = u & 31;
        bf16x8 pk;
        pk[0] = (__bf16)ld[j][0][0]; pk[1] = (__bf16)ld[j][0][1];
        pk[2] = (__bf16)ld[j][0][2]; pk[3] = (__bf16)ld[j][0][3];
        pk[4] = (__bf16)ld[j][1][0]; pk[5] = (__bf16)ld[j][1][1];
        pk[6] = (__bf16)ld[j][1][2]; pk[7] = (__bf16)ld[j][1][3];
        *(bf16x8*)&As[row * 256 + ((sl ^ (row & 7)) << 3)] = pk;
    }
    __syncthreads();     // the only barrier in the block

    const int lane  = tid & 63;
    const int wid   = tid >> 6;     // 0..7: wave's 64-col strip
    const int l15   = lane & 15;
    const int l4    = lane >> 4;    // 0..3
    const int nbase = wid * 64;
    const int r7    = l15 & 7;      // swizzle key (afr row&7 == l15&7)

    // fn-major: one 64x16 column strip at a time; acc = 4 x f32x4 = 16 VGPR.
#pragma unroll
    for (int fn = 0; fn < 4; ++fn) {
        const unsigned short* wp =
            W + (size_t)(nbase + fn * 16 + l15) * 256 + l4 * 8;

        f32x4 acc[4] = {};          // [fm]

#pragma unroll 1
        for (int ks = 0; ks < 8; ++ks) {
            const u16x8 bfr = *(const u16x8*)(wp + ks * 32);   // L1/L2-hit
            u16x8 afr[4];
#pragma unroll
            for (int fm = 0; fm < 4; ++fm) {
                const int row  = fm * 16 + l15;
                const int slot = (ks * 4 + l4) ^ r7;
                afr[fm] = *(const u16x8*)&As[row * 256 + slot * 8];
            }
#pragma unroll
            for (int fm = 0; fm < 4; ++fm) {
                // swapped operands: acc row = out-channel (4 consecutive per
                // lane via reg idx), col = activation row -> float4 C stores
                acc[fm] = __builtin_amdgcn_mfma_f32_16x16x32_bf16(
                    __builtin_bit_cast(bf16x8, bfr),
                    __builtin_bit_cast(bf16x8, afr[fm]),
                    acc[fm], 0, 0, 0);
            }
        }

        // store this strip (cached -> L2 merges 64 B halves into full lines);
        // overlaps with next fn's compute
        const int col = nbase + fn * 16 + l4 * 4;
        const f32x4 bv = *(const f32x4*)(bias + col);
#pragma unroll
        for (int fm = 0; fm < 4; ++fm) {
            const int row = m0 + fm * 16 + l15;
            *(f32x4*)(C + (size_t)row * 512 + col) = acc[fm] + bv;
        }
    }
}

extern "C" void kernel_launch(void* const* d_in, const int* in_sizes, int n_in,
                              void* d_out, int out_size, void* d_ws, size_t ws_size,
                              hipStream_t stream) {
    const float* A   = (const float*)d_in[0];
    const int*   tm  = (const int*)d_in[1];
    const int*   im  = (const int*)d_in[2];
    const float* Wt_ = (const float*)d_in[3];
    const float* bt  = (const float*)d_in[4];
    const float* Wi_ = (const float*)d_in[5];
    const float* bi  = (const float*)d_in[6];
    const float* Wo_ = (const float*)d_in[7];
    const float* bo  = (const float*)d_in[8];

    unsigned short* Wws = (unsigned short*)d_ws;   // 3*512*256*2 = 768 KB

    hipLaunchKernelGGL(convert_w_kernel, dim3(96), dim3(256),
                       0, stream, Wt_, Wi_, Wo_, Wws);

    hipLaunchKernelGGL(role_proj_kernel, dim3(2048), dim3(512),
                       0, stream, A, tm, im, Wws, bt, bi, bo, (float*)d_out);
}

// Round 6
// 123.239 us; speedup vs baseline: 2.6004x; 1.1148x over previous
//
#include <hip/hip_runtime.h>

typedef float f32x4 __attribute__((ext_vector_type(4)));
typedef unsigned short u16x8 __attribute__((ext_vector_type(8)));
typedef __bf16 bf16x8 __attribute__((ext_vector_type(8)));
typedef __bf16 bf16x4 __attribute__((ext_vector_type(4)));

// ---------------------------------------------------------------------------
// Kernel 1: convert + transpose three W (fp32 [256 k][512 n]) into bf16 W^T
// [role][512 n][256 k] in workspace, via 64x64 LDS tile transpose.
// ---------------------------------------------------------------------------
__global__ __launch_bounds__(256) void convert_w_kernel(
    const float* __restrict__ Wt_, const float* __restrict__ Wi_,
    const float* __restrict__ Wo_, unsigned short* __restrict__ out)
{
    __shared__ unsigned short tile[64][72];

    const int b    = blockIdx.x;
    const int role = b >> 5;
    const int kt   = (b & 31) >> 3;
    const int nt   = b & 7;
    const float* __restrict__ W = (role == 0) ? Wt_ : ((role == 1) ? Wi_ : Wo_);

    const int t  = threadIdx.x;
    const int r0 = t >> 4;
    const int c4 = (t & 15) << 2;

#pragma unroll
    for (int j = 0; j < 4; ++j) {
        const int kl = r0 + j * 16;
        f32x4 v = *(const f32x4*)(W + (size_t)(kt * 64 + kl) * 512 + nt * 64 + c4);
#pragma unroll
        for (int e = 0; e < 4; ++e)
            tile[c4 + e][kl] = __builtin_bit_cast(unsigned short, (__bf16)v[e]);
    }
    __syncthreads();

    const int cs = t & 7;
#pragma unroll
    for (int p = 0; p < 2; ++p) {
        const int r = (t >> 3) + p * 32;
        u16x8 v = *(const u16x8*)&tile[r][cs * 8];
        *(u16x8*)(out + (size_t)role * 512 * 256 +
                  (size_t)(nt * 64 + r) * 256 + kt * 64 + cs * 8) = v;
    }
}

// ---------------------------------------------------------------------------
// Kernel 2: role-selected GEMM with FULL-DENSITY HBM instructions.
// Block = 64 rows x 512 cols (A read once), 512 threads = 8 waves.
// Every global load/store instruction covers a contiguous 1 KB (full 128 B
// lines) -- rounds 1-5 all used half-density (64 B/line) patterns and all
// capped at ~3.0 TB/s = half the 6.3 TB/s mixed ceiling.
//   load  : lane-consecutive 16 B NT loads -> convert -> swizzled LDS (b64)
//   store : acc -> swizzled LDS (4 passes of 16 rows, reusing the A buffer)
//           -> lane-consecutive 16 B NT stores (1 KB contiguous per instr).
// Epilogue barriers are raw s_barrier + lgkmcnt(0) so C stores stay in
// flight across passes (no vmcnt(0) drain).
// ---------------------------------------------------------------------------
__global__ __launch_bounds__(512, 4) void role_proj_kernel(
    const float* __restrict__ A,            // [131072][256] fp32
    const int* __restrict__ tmask,          // [64]
    const int* __restrict__ imask,          // [64]
    const unsigned short* __restrict__ Wws, // [3][512][256] bf16 (W^T)
    const float* __restrict__ bt, const float* __restrict__ bi,
    const float* __restrict__ bo,
    float* __restrict__ C)                  // [131072][512] fp32
{
    __shared__ __align__(16) unsigned char smem[32 * 1024];
    unsigned short* As = (unsigned short*)smem;   // bf16 view (staging/compute)

    const int tid = threadIdx.x;
    const int m0  = blockIdx.x * 64;

    // role uniform per block: mask index = t/32 = blockIdx/32
    const int mi   = blockIdx.x >> 5;
    const int role = tmask[mi] ? 0 : (imask[mi] ? 1 : 2);
    const unsigned short* __restrict__ W = Wws + (size_t)role * (512 * 256);
    const float* __restrict__ bias = (role == 0) ? bt : ((role == 1) ? bi : bo);

    // ---- Phase 1: stage A (64 x 256 fp32 = 64 KB), full-density loads.
    // Instruction p: 64 lanes x consecutive 16 B = 1 KB contiguous.
    const f32x4* abase = (const f32x4*)(A + (size_t)m0 * 256);
    f32x4 ld[8];
#pragma unroll
    for (int p = 0; p < 8; ++p)
        ld[p] = __builtin_nontemporal_load(abase + tid + 512 * p);
#pragma unroll
    for (int p = 0; p < 8; ++p) {
        const int u    = tid + 512 * p;       // float4-unit index in tile
        const int row  = u >> 6;              // 64 units per 256-float row
        const int slot = ((u & 63) >> 1) ^ (row & 7);   // 16 B slot, swizzled
        bf16x4 pk = { (__bf16)ld[p][0], (__bf16)ld[p][1],
                      (__bf16)ld[p][2], (__bf16)ld[p][3] };
        *(bf16x4*)(smem + row * 512 + slot * 16 + (u & 1) * 8) = pk;
    }
    __syncthreads();   // no outstanding stores at this point -> free drain

    // ---- Phase 2: compute. Wave = 64 rows x 64 cols (wid strip).
    const int lane  = tid & 63;
    const int wid   = tid >> 6;
    const int l15   = lane & 15;
    const int l4    = lane >> 4;
    const int nbase = wid * 64;
    const int r7    = l15 & 7;

    const unsigned short* wp[4];
#pragma unroll
    for (int fn = 0; fn < 4; ++fn)
        wp[fn] = W + (size_t)(nbase + fn * 16 + l15) * 256 + l4 * 8;

    f32x4 acc[4][4] = {};          // [fm][fn]

#pragma unroll 1
    for (int ks = 0; ks < 8; ++ks) {
        u16x8 bfr[4];
#pragma unroll
        for (int fn = 0; fn < 4; ++fn)
            bfr[fn] = *(const u16x8*)(wp[fn] + ks * 32);   // L1/L2-resident
        u16x8 afr[4];
#pragma unroll
        for (int fm = 0; fm < 4; ++fm) {
            const int row  = fm * 16 + l15;
            const int slot = (ks * 4 + l4) ^ r7;
            afr[fm] = *(const u16x8*)&As[row * 256 + slot * 8];
        }
#pragma unroll
        for (int fm = 0; fm < 4; ++fm) {
#pragma unroll
            for (int fn = 0; fn < 4; ++fn) {
                // swapped operands: acc row = out-channel (4 consecutive per
                // lane via reg idx), col = activation row
                acc[fm][fn] = __builtin_amdgcn_mfma_f32_16x16x32_bf16(
                    __builtin_bit_cast(bf16x8, bfr[fn]),
                    __builtin_bit_cast(bf16x8, afr[fm]),
                    acc[fm][fn], 0, 0, 0);
            }
        }
    }

    // all waves done reading As (each wave's ds_reads retired by data dep)
    __builtin_amdgcn_sched_barrier(0);
    __builtin_amdgcn_s_barrier();
    __builtin_amdgcn_sched_barrier(0);

    // bias (loaded now to keep compute-phase VGPRs low)
    f32x4 bv[4];
#pragma unroll
    for (int fn = 0; fn < 4; ++fn)
        bv[fn] = *(const f32x4*)(bias + nbase + fn * 16 + l4 * 4);

    // ---- Phase 3: epilogue, 4 passes of 16 rows through LDS (fp32 view).
    // Store instructions: 64 lanes x consecutive 16 B = 1 KB contiguous.
#pragma unroll
    for (int p = 0; p < 4; ++p) {
        // write acc[p][*] into LDS [16 rows][512 cols] fp32, chunk-swizzled
#pragma unroll
        for (int fn = 0; fn < 4; ++fn) {
            const int chunk = (wid * 16 + fn * 4 + l4) ^ r7;  // 4-float chunks
            *(f32x4*)(smem + l15 * 2048 + chunk * 16) = acc[p][fn] + bv[fn];
        }
        asm volatile("s_waitcnt lgkmcnt(0)" ::: "memory");
        __builtin_amdgcn_sched_barrier(0);
        __builtin_amdgcn_s_barrier();
        __builtin_amdgcn_sched_barrier(0);

        // linear read + fully-contiguous NT stores
#pragma unroll
        for (int q = 0; q < 4; ++q) {
            const int f4    = tid + 512 * q;   // float4 unit in 16x512 buffer
            const int row   = f4 >> 7;         // 128 units per 512-float row
            const int chunk = f4 & 127;
            f32x4 v = *(const f32x4*)(smem + row * 2048 + (chunk ^ (row & 7)) * 16);
            __builtin_nontemporal_store(
                v, (f32x4*)(C + ((size_t)(m0 + p * 16 + row) << 9) + chunk * 4));
        }
        if (p < 3) {   // reuse LDS next pass; stores stay in flight (no vmcnt)
            __builtin_amdgcn_sched_barrier(0);
            __builtin_amdgcn_s_barrier();
            __builtin_amdgcn_sched_barrier(0);
        }
    }
}

extern "C" void kernel_launch(void* const* d_in, const int* in_sizes, int n_in,
                              void* d_out, int out_size, void* d_ws, size_t ws_size,
                              hipStream_t stream) {
    const float* A   = (const float*)d_in[0];
    const int*   tm  = (const int*)d_in[1];
    const int*   im  = (const int*)d_in[2];
    const float* Wt_ = (const float*)d_in[3];
    const float* bt  = (const float*)d_in[4];
    const float* Wi_ = (const float*)d_in[5];
    const float* bi  = (const float*)d_in[6];
    const float* Wo_ = (const float*)d_in[7];
    const float* bo  = (const float*)d_in[8];

    unsigned short* Wws = (unsigned short*)d_ws;   // 3*512*256*2 = 768 KB

    hipLaunchKernelGGL(convert_w_kernel, dim3(96), dim3(256),
                       0, stream, Wt_, Wi_, Wo_, Wws);

    hipLaunchKernelGGL(role_proj_kernel, dim3(2048), dim3(512),
                       0, stream, A, tm, im, Wws, bt, bi, bo, (float*)d_out);
}